// Round 1
// baseline (380.388 us; speedup 1.0000x reference)
//
#include <hip/hip_runtime.h>
#include <math.h>

#define B_  4
#define CK_ 64
#define N_  4032   // memory axis (softmax axis)
#define M_  4032   // query axis

#define P1_CHUNKS 7    // pass1: 7 n-chunks x 9 tiles of 64 rows
#define P1_TILES  9
#define P2_GROUPS 9    // pass2: 9 n-groups x 7 tiles of 64 rows
#define P2_TILES  7

typedef __attribute__((ext_vector_type(8))) short short8;   // 8 bf16 = 4 VGPRs (MFMA A/B frag)
typedef __attribute__((ext_vector_type(4))) float float4v;  // MFMA C/D frag

// fp32 -> bf16 bits, round-to-nearest-even (inputs are finite normals)
__device__ inline unsigned short f2bf(float x) {
    unsigned u = __float_as_uint(x);
    u += 0x7FFF + ((u >> 16) & 1);
    return (unsigned short)(u >> 16);
}
__device__ inline float bf2f(unsigned short h) {
    return __uint_as_float(((unsigned)h) << 16);
}

// ---------------- Prep: transpose to [n][64] bf16 hi/lo + u_n --------------
// in [B][64][N] fp32 -> dst_hi/dst_lo [B][N][64] bf16; for mk also
// u[b][n] = exp(-0.125 * sum_c mk^2)  (softmax col-constant qk^2 term dropped).
__global__ __launch_bounds__(256) void prep_kernel(
    const float* __restrict__ mk, const float* __restrict__ qk,
    unsigned short* __restrict__ mk_hi, unsigned short* __restrict__ mk_lo,
    unsigned short* __restrict__ qk_hi, unsigned short* __restrict__ qk_lo,
    float* __restrict__ u)
{
    __shared__ float tile[64][65];
    __shared__ float sred[4][64];
    const int t  = threadIdx.x;
    const int n0 = blockIdx.x * 64;
    const int b  = blockIdx.y;
    const int which = blockIdx.z;

    const float* src = (which == 0 ? mk : qk) + (size_t)b * CK_ * N_;
    unsigned short* dhi = (which == 0 ? mk_hi : qk_hi) + (size_t)b * N_ * CK_;
    unsigned short* dlo = (which == 0 ? mk_lo : qk_lo) + (size_t)b * N_ * CK_;

    #pragma unroll
    for (int i = 0; i < 16; ++i) {
        const int idx = t + 256 * i;
        const int c = idx >> 6, n = idx & 63;
        tile[c][n] = src[(size_t)c * N_ + n0 + n];
    }
    __syncthreads();

    const int n = t & 63;
    const int g = t >> 6;          // c-group of 16
    unsigned short hbits[16], lbits[16];
    float ssq = 0.f;
    #pragma unroll
    for (int i = 0; i < 16; ++i) {
        const float x = tile[g * 16 + i][n];
        const unsigned short h = f2bf(x);
        hbits[i] = h;
        lbits[i] = f2bf(x - bf2f(h));
        ssq = fmaf(x, x, ssq);
    }
    {
        union { short8 v; unsigned short s[8]; } p0, p1, q0, q1;
        #pragma unroll
        for (int i = 0; i < 8; ++i) {
            p0.s[i] = hbits[i]; p1.s[i] = hbits[8 + i];
            q0.s[i] = lbits[i]; q1.s[i] = lbits[8 + i];
        }
        const size_t base = (size_t)(n0 + n) * CK_ + g * 16;
        *(short8*)(dhi + base)     = p0.v;
        *(short8*)(dhi + base + 8) = p1.v;
        *(short8*)(dlo + base)     = q0.v;
        *(short8*)(dlo + base + 8) = q1.v;
    }
    sred[g][n] = ssq;
    __syncthreads();
    if (which == 0 && t < 64) {
        const float tot = sred[0][t] + sred[1][t] + sred[2][t] + sred[3][t];
        u[(size_t)b * N_ + n0 + t] = __expf(-0.125f * tot);
    }
}

// MFMA 16x16x32 bf16 layouts (verified m89/m91):
//   A: A[m = lane&15][k = (lane>>4)*8 + j], j in [0,8)  -> 16B contiguous per lane
//   B: B[k = (lane>>4)*8 + j][n = lane&15]              -> same addressing on [row][64] arrays
//   C/D: col = lane&15, row = (lane>>4)*4 + reg

// ---------------- Pass 1: partial softmax denominators ----------------------
// Grid (M/64, P1_CHUNKS, B). Block: 64 m-cols, 9 n-tiles; 4 waves in 2x2
// (wn splits n, wm splits m). Writes partial colsums psum[b][chunk][m].
__global__ __launch_bounds__(256) void pass1_kernel(
    const unsigned short* __restrict__ mk_hi, const unsigned short* __restrict__ mk_lo,
    const unsigned short* __restrict__ qk_hi, const unsigned short* __restrict__ qk_lo,
    const float* __restrict__ u, float* __restrict__ psum)
{
    __shared__ float cs[2][64];
    const int t = threadIdx.x;
    const int wave = t >> 6, lane = t & 63;
    const int wn = wave & 1, wm = wave >> 1;
    const int lcol = lane & 15;
    const int quad = lane >> 4;
    const int chunk = blockIdx.y;
    const int b = blockIdx.z;
    const int m_base = blockIdx.x * 64 + wm * 32;

    const unsigned short* mh = mk_hi + (size_t)b * N_ * CK_;
    const unsigned short* ml = mk_lo + (size_t)b * N_ * CK_;
    const unsigned short* qh = qk_hi + (size_t)b * M_ * CK_;
    const unsigned short* ql = qk_lo + (size_t)b * M_ * CK_;
    const float* ub = u + (size_t)b * N_;

    // hoist B (qk) fragments: cg = 16-col group, kc = k-chunk of 32
    short8 bh[2][2], bl[2][2];
    #pragma unroll
    for (int cg = 0; cg < 2; ++cg) {
        const size_t mrow = (size_t)(m_base + cg * 16 + lcol) * CK_;
        #pragma unroll
        for (int kc = 0; kc < 2; ++kc) {
            const size_t off = mrow + kc * 32 + quad * 8;
            bh[cg][kc] = *(const short8*)(qh + off);
            bl[cg][kc] = *(const short8*)(ql + off);
        }
    }

    float p0 = 0.f, p1 = 0.f;   // per-lane col partials (cg=0,1)

    #pragma unroll 1
    for (int it = chunk * P1_TILES; it < chunk * P1_TILES + P1_TILES; ++it) {
        const int n_base = it * 64 + wn * 32;
        short8 ah[2][2], al[2][2];
        #pragma unroll
        for (int rg = 0; rg < 2; ++rg) {
            const size_t nrow = (size_t)(n_base + rg * 16 + lcol) * CK_;
            #pragma unroll
            for (int kc = 0; kc < 2; ++kc) {
                const size_t off = nrow + kc * 32 + quad * 8;
                ah[rg][kc] = *(const short8*)(mh + off);
                al[rg][kc] = *(const short8*)(ml + off);
            }
        }
        float uv[2][4];
        #pragma unroll
        for (int rg = 0; rg < 2; ++rg)
            #pragma unroll
            for (int r = 0; r < 4; ++r)
                uv[rg][r] = ub[n_base + rg * 16 + quad * 4 + r];

        #pragma unroll
        for (int rg = 0; rg < 2; ++rg) {
            #pragma unroll
            for (int cg = 0; cg < 2; ++cg) {
                float4v a1 = {0.f, 0.f, 0.f, 0.f};
                float4v a2 = {0.f, 0.f, 0.f, 0.f};
                #pragma unroll
                for (int kc = 0; kc < 2; ++kc) {
                    a1 = __builtin_amdgcn_mfma_f32_16x16x32_bf16(ah[rg][kc], bh[cg][kc], a1, 0, 0, 0);
                    a2 = __builtin_amdgcn_mfma_f32_16x16x32_bf16(ah[rg][kc], bl[cg][kc], a2, 0, 0, 0);
                    a2 = __builtin_amdgcn_mfma_f32_16x16x32_bf16(al[rg][kc], bh[cg][kc], a2, 0, 0, 0);
                }
                float ps = 0.f;
                #pragma unroll
                for (int r = 0; r < 4; ++r) {
                    const float dot = a1[r] + a2[r];
                    ps += uv[rg][r] * __expf(0.25f * dot);
                }
                if (cg == 0) p0 += ps; else p1 += ps;
            }
        }
    }

    // reduce across the 4 quads (rows) -> every lane holds its col total
    p0 += __shfl_xor(p0, 16); p0 += __shfl_xor(p0, 32);
    p1 += __shfl_xor(p1, 16); p1 += __shfl_xor(p1, 32);
    if (lane < 16) {
        cs[wn][wm * 32 + lcol]      = p0;
        cs[wn][wm * 32 + 16 + lcol] = p1;
    }
    __syncthreads();
    if (t < 64) {
        psum[((size_t)b * P1_CHUNKS + chunk) * M_ + blockIdx.x * 64 + t] =
            cs[0][t] + cs[1][t];
    }
}

// ---------------- Pass 2: recompute + normalized write ----------------------
// Grid (M/64, P2_GROUPS, B). Block: 64 m-cols x (7 tiles x 64 n-rows);
// 4 waves in 2x2, each wave a 32x32 tile per n-tile.
// OPERANDS SWAPPED vs pass1: A = qk (m rows), B = mk (n rows) so that
// D[m][n] gives each lane 4 CONSECUTIVE m per accum -> float4 stores.
__global__ __launch_bounds__(256) void pass2_kernel(
    const unsigned short* __restrict__ mk_hi, const unsigned short* __restrict__ mk_lo,
    const unsigned short* __restrict__ qk_hi, const unsigned short* __restrict__ qk_lo,
    const float* __restrict__ u, const float* __restrict__ psum,
    float* __restrict__ out)
{
    const int t = threadIdx.x;
    const int wave = t >> 6, lane = t & 63;
    const int wn = wave & 1, wm = wave >> 1;
    const int lcol = lane & 15;
    const int quad = lane >> 4;
    const int b = blockIdx.z;
    const int m_base = blockIdx.x * 64 + wm * 32;

    const unsigned short* mh = mk_hi + (size_t)b * N_ * CK_;
    const unsigned short* ml = mk_lo + (size_t)b * N_ * CK_;
    const unsigned short* qh = qk_hi + (size_t)b * M_ * CK_;
    const unsigned short* ql = qk_lo + (size_t)b * M_ * CK_;
    const float* ub = u + (size_t)b * N_;

    // hoist A (qk) fragments: mg = 16-row group (m), kc = k-chunk of 32
    short8 qah[2][2], qal[2][2];
    #pragma unroll
    for (int mg = 0; mg < 2; ++mg) {
        const size_t mrow = (size_t)(m_base + mg * 16 + lcol) * CK_;
        #pragma unroll
        for (int kc = 0; kc < 2; ++kc) {
            const size_t off = mrow + kc * 32 + quad * 8;
            qah[mg][kc] = *(const short8*)(qh + off);
            qal[mg][kc] = *(const short8*)(ql + off);
        }
    }

    // per-lane denominators: m = m_base + mg*16 + quad*4 + r  (4 consecutive)
    float4v rinv4[2];
    #pragma unroll
    for (int mg = 0; mg < 2; ++mg) {
        float4v tot = {0.f, 0.f, 0.f, 0.f};
        #pragma unroll
        for (int c = 0; c < P1_CHUNKS; ++c) {
            const float4v p = *(const float4v*)(
                psum + ((size_t)b * P1_CHUNKS + c) * M_ + m_base + mg * 16 + quad * 4);
            tot += p;
        }
        rinv4[mg][0] = 1.f / tot[0];
        rinv4[mg][1] = 1.f / tot[1];
        rinv4[mg][2] = 1.f / tot[2];
        rinv4[mg][3] = 1.f / tot[3];
    }

    float* obase = out + (size_t)b * N_ * M_ + m_base + quad * 4;

    #pragma unroll 1
    for (int j = 0; j < P2_TILES; ++j) {
        const int n_base = (blockIdx.y * P2_TILES + j) * 64 + wn * 32;

        // B (mk) fragments: ng = 16-col group (n), kc = k-chunk of 32
        short8 bh[2][2], bl[2][2];
        #pragma unroll
        for (int ng = 0; ng < 2; ++ng) {
            const size_t nrow = (size_t)(n_base + ng * 16 + lcol) * CK_;
            #pragma unroll
            for (int kc = 0; kc < 2; ++kc) {
                const size_t off = nrow + kc * 32 + quad * 8;
                bh[ng][kc] = *(const short8*)(mh + off);
                bl[ng][kc] = *(const short8*)(ml + off);
            }
        }
        float un[2];
        #pragma unroll
        for (int ng = 0; ng < 2; ++ng)
            un[ng] = ub[n_base + ng * 16 + lcol];

        #pragma unroll
        for (int mg = 0; mg < 2; ++mg) {
            #pragma unroll
            for (int ng = 0; ng < 2; ++ng) {
                float4v a1 = {0.f, 0.f, 0.f, 0.f};
                float4v a2 = {0.f, 0.f, 0.f, 0.f};
                #pragma unroll
                for (int kc = 0; kc < 2; ++kc) {
                    a1 = __builtin_amdgcn_mfma_f32_16x16x32_bf16(qah[mg][kc], bh[ng][kc], a1, 0, 0, 0);
                    a2 = __builtin_amdgcn_mfma_f32_16x16x32_bf16(qah[mg][kc], bl[ng][kc], a2, 0, 0, 0);
                    a2 = __builtin_amdgcn_mfma_f32_16x16x32_bf16(qal[mg][kc], bh[ng][kc], a2, 0, 0, 0);
                }
                float4v v;
                #pragma unroll
                for (int r = 0; r < 4; ++r) {
                    const float dot = a1[r] + a2[r];
                    v[r] = un[ng] * __expf(0.25f * dot) * rinv4[mg][r];
                }
                float4v* dst = (float4v*)(
                    obase + (size_t)(n_base + ng * 16 + lcol) * M_ + mg * 16);
                __builtin_nontemporal_store(v, dst);
            }
        }
    }
}

extern "C" void kernel_launch(void* const* d_in, const int* in_sizes, int n_in,
                              void* d_out, int out_size, void* d_ws, size_t ws_size,
                              hipStream_t stream) {
    const float* mk = (const float*)d_in[0];
    const float* qk = (const float*)d_in[1];
    float* out = (float*)d_out;

    // ws layout: mk_hi | mk_lo | qk_hi | qk_lo (bf16 [B][N][64]) | u | psum (f32)
    unsigned short* mk_hi = (unsigned short*)d_ws;
    unsigned short* mk_lo = mk_hi + (size_t)B_ * N_ * CK_;
    unsigned short* qk_hi = mk_lo + (size_t)B_ * N_ * CK_;
    unsigned short* qk_lo = qk_hi + (size_t)B_ * M_ * CK_;
    float* u    = (float*)(qk_lo + (size_t)B_ * M_ * CK_);
    float* psum = u + (size_t)B_ * N_;   // [B][P1_CHUNKS][M]

    prep_kernel<<<dim3(N_ / 64, B_, 2), 256, 0, stream>>>(mk, qk, mk_hi, mk_lo, qk_hi, qk_lo, u);
    pass1_kernel<<<dim3(M_ / 64, P1_CHUNKS, B_), 256, 0, stream>>>(mk_hi, mk_lo, qk_hi, qk_lo, u, psum);
    pass2_kernel<<<dim3(M_ / 64, P2_GROUPS, B_), 256, 0, stream>>>(mk_hi, mk_lo, qk_hi, qk_lo, u, psum, out);
}

// Round 6
// 377.161 us; speedup vs baseline: 1.0086x; 1.0086x over previous
//
#include <hip/hip_runtime.h>
#include <math.h>

#define B_  4
#define CK_ 64
#define N_  4032   // memory axis (softmax axis), real
#define M_  4032   // query axis, real
#define NP_ 4096   // padded rows (4032..4095 zero-filled)
#define MP_ 4096

#define P1C 8   // pass1: 8 n-chunks x 8 tiles of 64 rows
#define P1T 8
#define P2G 8   // pass2: 8 n-groups x 8 tiles of 64 rows
#define P2T 8

typedef __attribute__((ext_vector_type(8))) short short8;   // 8 bf16 = 4 VGPRs (MFMA A/B frag)
typedef __attribute__((ext_vector_type(4))) float float4v;  // MFMA C/D frag

// fp32 -> bf16 bits, round-to-nearest-even (inputs are finite normals)
__device__ inline unsigned short f2bf(float x) {
    unsigned u = __float_as_uint(x);
    u += 0x7FFF + ((u >> 16) & 1);
    return (unsigned short)(u >> 16);
}
__device__ inline float bf2f(unsigned short h) {
    return __uint_as_float(((unsigned)h) << 16);
}

// ---------------- Prep: transpose to [n][64] bf16 hi/lo + u_n --------------
// in [B][64][N] fp32 -> dst_hi/dst_lo [B][NP][64] bf16 (rows >= N_ zeroed);
// for mk also u[b][n] = exp(-0.125 * sum_c mk^2), u = 0 on pad rows.
__global__ __launch_bounds__(256) void prep_kernel(
    const float* __restrict__ mk, const float* __restrict__ qk,
    unsigned short* __restrict__ mk_hi, unsigned short* __restrict__ mk_lo,
    unsigned short* __restrict__ qk_hi, unsigned short* __restrict__ qk_lo,
    float* __restrict__ u)
{
    __shared__ float tile[64][65];
    __shared__ float sred[4][64];
    const int t  = threadIdx.x;
    const int n0 = blockIdx.x * 64;
    const int b  = blockIdx.y;
    const int which = blockIdx.z;
    const bool pad = (n0 >= N_);            // block-uniform

    const float* src = (which == 0 ? mk : qk) + (size_t)b * CK_ * N_;
    unsigned short* dhi = (which == 0 ? mk_hi : qk_hi) + (size_t)b * NP_ * CK_;
    unsigned short* dlo = (which == 0 ? mk_lo : qk_lo) + (size_t)b * NP_ * CK_;

    if (!pad) {
        #pragma unroll
        for (int i = 0; i < 16; ++i) {
            const int idx = t + 256 * i;
            const int c = idx >> 6, n = idx & 63;
            tile[c][n] = src[(size_t)c * N_ + n0 + n];
        }
    } else {
        #pragma unroll
        for (int i = 0; i < 16; ++i) {
            const int idx = t + 256 * i;
            tile[idx >> 6][idx & 63] = 0.f;
        }
    }
    __syncthreads();

    const int n = t & 63;
    const int g = t >> 6;          // c-group of 16
    unsigned short hbits[16], lbits[16];
    float ssq = 0.f;
    #pragma unroll
    for (int i = 0; i < 16; ++i) {
        const float x = tile[g * 16 + i][n];
        const unsigned short h = f2bf(x);
        hbits[i] = h;
        lbits[i] = f2bf(x - bf2f(h));
        ssq = fmaf(x, x, ssq);
    }
    {
        union { short8 v; unsigned short s[8]; } p0, p1, q0, q1;
        #pragma unroll
        for (int i = 0; i < 8; ++i) {
            p0.s[i] = hbits[i]; p1.s[i] = hbits[8 + i];
            q0.s[i] = lbits[i]; q1.s[i] = lbits[8 + i];
        }
        const size_t base = (size_t)(n0 + n) * CK_ + g * 16;
        *(short8*)(dhi + base)     = p0.v;
        *(short8*)(dhi + base + 8) = p1.v;
        *(short8*)(dlo + base)     = q0.v;
        *(short8*)(dlo + base + 8) = q1.v;
    }
    sred[g][n] = ssq;
    __syncthreads();
    if (which == 0 && t < 64) {
        const float tot = sred[0][t] + sred[1][t] + sred[2][t] + sred[3][t];
        u[(size_t)b * NP_ + n0 + t] = pad ? 0.f : __expf(-0.125f * tot);
    }
}

// MFMA 16x16x32 bf16 layouts (verified m89/m91):
//   A: A[m = lane&15][k = (lane>>4)*8 + j], j in [0,8)  -> 16B contiguous per lane
//   B: B[k = (lane>>4)*8 + j][n = lane&15]              -> same addressing on [row][64] arrays
//   C/D: col = lane&15, row = (lane>>4)*4 + reg

// ---------------- Pass 1: partial softmax denominators ----------------------
// Grid (MP/128, P1C, B). Block 512 = 8 waves: wm in 0..3 (m 32-strips),
// wn in 0..1 (n halves of each 64-tile). Writes psum[b][chunk][MP].
__global__ __launch_bounds__(512) void pass1_kernel(
    const unsigned short* __restrict__ mk_hi, const unsigned short* __restrict__ mk_lo,
    const unsigned short* __restrict__ qk_hi, const unsigned short* __restrict__ qk_lo,
    const float* __restrict__ u, float* __restrict__ psum)
{
    __shared__ float cs[2][128];
    const int t = threadIdx.x;
    const int wave = t >> 6, lane = t & 63;
    const int wn = wave & 1, wm = wave >> 1;
    const int lcol = lane & 15;
    const int quad = lane >> 4;
    const int chunk = blockIdx.y;
    const int b = blockIdx.z;
    const int m_base = blockIdx.x * 128 + wm * 32;

    const unsigned short* mh = mk_hi + (size_t)b * NP_ * CK_;
    const unsigned short* ml = mk_lo + (size_t)b * NP_ * CK_;
    const unsigned short* qh = qk_hi + (size_t)b * NP_ * CK_;
    const unsigned short* ql = qk_lo + (size_t)b * NP_ * CK_;
    const float* ub = u + (size_t)b * NP_;

    // hoist B (qk) fragments: cg = 16-col group, kc = k-chunk of 32
    short8 bh[2][2], bl[2][2];
    #pragma unroll
    for (int cg = 0; cg < 2; ++cg) {
        const size_t mrow = (size_t)(m_base + cg * 16 + lcol) * CK_;
        #pragma unroll
        for (int kc = 0; kc < 2; ++kc) {
            const size_t off = mrow + kc * 32 + quad * 8;
            bh[cg][kc] = *(const short8*)(qh + off);
            bl[cg][kc] = *(const short8*)(ql + off);
        }
    }

    float p0 = 0.f, p1 = 0.f;   // per-lane col partials (cg=0,1)

    #pragma unroll 2
    for (int it = chunk * P1T; it < chunk * P1T + P1T; ++it) {
        const int n_base = it * 64 + wn * 32;
        short8 ah[2][2], al[2][2];
        #pragma unroll
        for (int rg = 0; rg < 2; ++rg) {
            const size_t nrow = (size_t)(n_base + rg * 16 + lcol) * CK_;
            #pragma unroll
            for (int kc = 0; kc < 2; ++kc) {
                const size_t off = nrow + kc * 32 + quad * 8;
                ah[rg][kc] = *(const short8*)(mh + off);
                al[rg][kc] = *(const short8*)(ml + off);
            }
        }
        float4v uv0 = *(const float4v*)(ub + n_base + quad * 4);
        float4v uv1 = *(const float4v*)(ub + n_base + 16 + quad * 4);

        #pragma unroll
        for (int rg = 0; rg < 2; ++rg) {
            #pragma unroll
            for (int cg = 0; cg < 2; ++cg) {
                float4v a1 = {0.f, 0.f, 0.f, 0.f};
                float4v a2 = {0.f, 0.f, 0.f, 0.f};
                __builtin_amdgcn_s_setprio(1);
                #pragma unroll
                for (int kc = 0; kc < 2; ++kc) {
                    a1 = __builtin_amdgcn_mfma_f32_16x16x32_bf16(ah[rg][kc], bh[cg][kc], a1, 0, 0, 0);
                    a2 = __builtin_amdgcn_mfma_f32_16x16x32_bf16(ah[rg][kc], bl[cg][kc], a2, 0, 0, 0);
                    a2 = __builtin_amdgcn_mfma_f32_16x16x32_bf16(al[rg][kc], bh[cg][kc], a2, 0, 0, 0);
                }
                __builtin_amdgcn_s_setprio(0);
                float ps = 0.f;
                #pragma unroll
                for (int r = 0; r < 4; ++r) {
                    const float dot = a1[r] + a2[r];
                    const float uvr = (rg == 0) ? uv0[r] : uv1[r];
                    ps += uvr * __expf(0.25f * dot);
                }
                if (cg == 0) p0 += ps; else p1 += ps;
            }
        }
    }

    // reduce across the 4 quads (rows) -> every lane holds its col total
    p0 += __shfl_xor(p0, 16); p0 += __shfl_xor(p0, 32);
    p1 += __shfl_xor(p1, 16); p1 += __shfl_xor(p1, 32);
    if (lane < 16) {
        cs[wn][wm * 32 + lcol]      = p0;
        cs[wn][wm * 32 + 16 + lcol] = p1;
    }
    __syncthreads();
    if (t < 128) {
        psum[((size_t)b * P1C + chunk) * MP_ + blockIdx.x * 128 + t] =
            cs[0][t] + cs[1][t];
    }
}

// ---------------- Pass 2: recompute + normalized write ----------------------
// Grid (MP/128, P2G, B). Block 512 = 8 waves (wm 0..3, wn 0..1); per n-tile
// each wave computes a 32x32 tile. OPERANDS SWAPPED vs pass1: A = qk (m),
// B = mk (n) so D gives 4 CONSECUTIVE m per accum -> float4 stores.
__global__ __launch_bounds__(512) void pass2_kernel(
    const unsigned short* __restrict__ mk_hi, const unsigned short* __restrict__ mk_lo,
    const unsigned short* __restrict__ qk_hi, const unsigned short* __restrict__ qk_lo,
    const float* __restrict__ u, const float* __restrict__ psum,
    float* __restrict__ out)
{
    const int t = threadIdx.x;
    const int wave = t >> 6, lane = t & 63;
    const int wn = wave & 1, wm = wave >> 1;
    const int lcol = lane & 15;
    const int quad = lane >> 4;
    const int b = blockIdx.z;
    const int m_base = blockIdx.x * 128 + wm * 32;

    const unsigned short* mh = mk_hi + (size_t)b * NP_ * CK_;
    const unsigned short* ml = mk_lo + (size_t)b * NP_ * CK_;
    const unsigned short* qh = qk_hi + (size_t)b * NP_ * CK_;
    const unsigned short* ql = qk_lo + (size_t)b * NP_ * CK_;
    const float* ub = u + (size_t)b * NP_;

    // hoist A (qk) fragments: mg = 16-row group (m), kc = k-chunk of 32
    short8 qah[2][2], qal[2][2];
    #pragma unroll
    for (int mg = 0; mg < 2; ++mg) {
        const size_t mrow = (size_t)(m_base + mg * 16 + lcol) * CK_;
        #pragma unroll
        for (int kc = 0; kc < 2; ++kc) {
            const size_t off = mrow + kc * 32 + quad * 8;
            qah[mg][kc] = *(const short8*)(qh + off);
            qal[mg][kc] = *(const short8*)(ql + off);
        }
    }

    // per-lane denominators: m = m_base + mg*16 + quad*4 + r  (4 consecutive)
    float4v rinv4[2];
    #pragma unroll
    for (int mg = 0; mg < 2; ++mg) {
        float4v tot = {0.f, 0.f, 0.f, 0.f};
        #pragma unroll
        for (int c = 0; c < P1C; ++c) {
            const float4v p = *(const float4v*)(
                psum + ((size_t)b * P1C + c) * MP_ + m_base + mg * 16 + quad * 4);
            tot += p;
        }
        rinv4[mg][0] = 1.f / tot[0];
        rinv4[mg][1] = 1.f / tot[1];
        rinv4[mg][2] = 1.f / tot[2];
        rinv4[mg][3] = 1.f / tot[3];
    }

    const bool mval0 = (m_base < N_);            // mg=0 16-group fully valid
    const bool mval1 = (m_base + 16 < N_);       // mg=1 (boundaries 16-aligned)

    float* obase = out + (size_t)b * N_ * M_ + m_base + quad * 4;

    #pragma unroll 2
    for (int j = 0; j < P2T; ++j) {
        const int n_base = (blockIdx.y * P2T + j) * 64 + wn * 32;

        // B (mk) fragments: ng = 16-col group (n), kc = k-chunk of 32
        short8 bh[2][2], bl[2][2];
        #pragma unroll
        for (int ng = 0; ng < 2; ++ng) {
            const size_t nrow = (size_t)(n_base + ng * 16 + lcol) * CK_;
            #pragma unroll
            for (int kc = 0; kc < 2; ++kc) {
                const size_t off = nrow + kc * 32 + quad * 8;
                bh[ng][kc] = *(const short8*)(mh + off);
                bl[ng][kc] = *(const short8*)(ml + off);
            }
        }
        float un[2];
        #pragma unroll
        for (int ng = 0; ng < 2; ++ng)
            un[ng] = ub[n_base + ng * 16 + lcol];

        const bool nval = (n_base < N_);   // n-tiles are 32-aligned; 4032 % 32 == 0

        #pragma unroll
        for (int mg = 0; mg < 2; ++mg) {
            #pragma unroll
            for (int ng = 0; ng < 2; ++ng) {
                float4v a1 = {0.f, 0.f, 0.f, 0.f};
                float4v a2 = {0.f, 0.f, 0.f, 0.f};
                __builtin_amdgcn_s_setprio(1);
                #pragma unroll
                for (int kc = 0; kc < 2; ++kc) {
                    a1 = __builtin_amdgcn_mfma_f32_16x16x32_bf16(qah[mg][kc], bh[ng][kc], a1, 0, 0, 0);
                    a2 = __builtin_amdgcn_mfma_f32_16x16x32_bf16(qah[mg][kc], bl[ng][kc], a2, 0, 0, 0);
                    a2 = __builtin_amdgcn_mfma_f32_16x16x32_bf16(qal[mg][kc], bh[ng][kc], a2, 0, 0, 0);
                }
                __builtin_amdgcn_s_setprio(0);
                float4v v;
                #pragma unroll
                for (int r = 0; r < 4; ++r) {
                    const float dot = a1[r] + a2[r];
                    v[r] = un[ng] * __expf(0.25f * dot) * rinv4[mg][r];
                }
                if (nval && (mg == 0 ? mval0 : mval1)) {
                    float4v* dst = (float4v*)(
                        obase + (size_t)(n_base + ng * 16 + lcol) * M_ + mg * 16);
                    __builtin_nontemporal_store(v, dst);
                }
            }
        }
    }
}

extern "C" void kernel_launch(void* const* d_in, const int* in_sizes, int n_in,
                              void* d_out, int out_size, void* d_ws, size_t ws_size,
                              hipStream_t stream) {
    const float* mk = (const float*)d_in[0];
    const float* qk = (const float*)d_in[1];
    float* out = (float*)d_out;

    // ws layout: mk_hi | mk_lo | qk_hi | qk_lo (bf16 [B][NP][64]) | u | psum (f32)
    unsigned short* mk_hi = (unsigned short*)d_ws;
    unsigned short* mk_lo = mk_hi + (size_t)B_ * NP_ * CK_;
    unsigned short* qk_hi = mk_lo + (size_t)B_ * NP_ * CK_;
    unsigned short* qk_lo = qk_hi + (size_t)B_ * NP_ * CK_;
    float* u    = (float*)(qk_lo + (size_t)B_ * NP_ * CK_);
    float* psum = u + (size_t)B_ * NP_;   // [B][P1C][MP]

    prep_kernel<<<dim3(NP_ / 64, B_, 2), 256, 0, stream>>>(mk, qk, mk_hi, mk_lo, qk_hi, qk_lo, u);
    pass1_kernel<<<dim3(MP_ / 128, P1C, B_), 512, 0, stream>>>(mk_hi, mk_lo, qk_hi, qk_lo, u, psum);
    pass2_kernel<<<dim3(MP_ / 128, P2G, B_), 512, 0, stream>>>(mk_hi, mk_lo, qk_hi, qk_lo, u, psum, out);
}